// Round 10
// baseline (268.615 us; speedup 1.0000x reference)
//
#include <hip/hip_runtime.h>
#include <hip/hip_bf16.h>
#include <cstdint>

#define NNODES 50000
#define NEDGES 800000
#define ETOT   (NEDGES + NNODES)
#define LN_EPS 1e-5f
#define NEG_SLOPE 0.2f
#define ELLW   64   // ELL row width (128B line); slot0 = self-loop

typedef __attribute__((ext_vector_type(8))) short s16x8;
typedef __attribute__((ext_vector_type(4))) float f32x4;

__device__ __forceinline__ float bf2f(unsigned short u) {
    return __uint_as_float(((unsigned int)u) << 16);
}
__device__ __forceinline__ unsigned short f2bf(float f) {
    unsigned int u = __float_as_uint(f);
    u += 0x7FFFu + ((u >> 16) & 1u);   // round-to-nearest-even
    return (unsigned short)(u >> 16);
}
// unpack packed bf16x2 dword -> f32
__device__ __forceinline__ float plo32(unsigned u) { return __uint_as_float(u << 16); }
__device__ __forceinline__ float phi32(unsigned u) { return __uint_as_float(u & 0xffff0000u); }

// ---------------- prep: W -> bf16 panel-k-major tiles + counts/ELL init ----------------

#define W1SZ (192 * 256)
#define W2SZ (96 * 192)
#define W3SZ (48 * 96)

__global__ __launch_bounds__(256) void prep_kernel(const float* __restrict__ W1, const float* __restrict__ W2,
                                                   const float* __restrict__ W3, unsigned short* __restrict__ wt1,
                                                   unsigned short* __restrict__ wt2, unsigned short* __restrict__ wt3,
                                                   int* __restrict__ counts, unsigned short* __restrict__ ell) {
    int i = blockIdx.x * 256 + threadIdx.x;
    if (i < NNODES) {
        counts[i] = 1;                               // self-loop occupies slot 0
        ell[(size_t)i * ELLW] = (unsigned short)i;
    }
    if (i < W1SZ) {
        int c = i >> 8, k = i & 255;              // c: out-col 0..191, k: in 0..255
        int n = c >> 4, r = c & 15;
        wt1[((n * 32 + (k >> 3)) * 16 + r) * 8 + (k & 7)] = f2bf(W1[k * 192 + c]);
    } else if (i < W1SZ + W2SZ) {
        int j = i - W1SZ;
        int c = j / 192, k = j - c * 192;         // c 0..95, k 0..191
        int n = c >> 4, r = c & 15;
        wt2[((n * 24 + (k >> 3)) * 16 + r) * 8 + (k & 7)] = f2bf(W2[k * 96 + c]);
    } else if (i < W1SZ + W2SZ + W3SZ) {
        int j = i - (W1SZ + W2SZ);
        int c = j / 96, k = j - c * 96;           // c 0..47 (padded), k 0..95
        int n = c >> 4, r = c & 15;
        wt3[((n * 12 + (k >> 3)) * 16 + r) * 8 + (k & 7)] = (c < 40) ? f2bf(W3[k * 40 + c]) : (unsigned short)0;
    }
}

// ---------------- MFMA GEMM (F-split across waves) + fused s/t + ELL fill (layer 1 only) ----------------

template<int K, int F, int CS, int FP, int H, int D, int SPAD, int WSPLIT, int NHW, bool ABF, bool FILL>
__global__ __launch_bounds__(256, 4) void gemmst_kernel(const void* __restrict__ Xv,
                                                        const unsigned short* __restrict__ Wt,
                                                        unsigned short* __restrict__ C,
                                                        const float* __restrict__ asf, const float* __restrict__ adf,
                                                        float* __restrict__ sbuf, float* __restrict__ tbuf,
                                                        int nrows, int gblocks,
                                                        const int* __restrict__ eidx, int* counts,
                                                        unsigned short* __restrict__ ell, int e) {
    if constexpr (FILL) {
        if (blockIdx.x >= (unsigned)gblocks) {   // fill blocks appended last (best measured)
            int i = ((int)blockIdx.x - gblocks) * 256 + (int)threadIdx.x;
            if (i < e) {
                int sv = eidx[i];
                int d  = eidx[e + i];
                int slot = atomicAdd(&counts[d], 1);
                if (slot < ELLW) ell[(size_t)d * ELLW + slot] = (unsigned short)sv;
            }
            return;
        }
    }
    const int bix = (int)blockIdx.x;

    constexpr int NT  = FP / 16;
    constexpr int NTW = NT / WSPLIT;     // panels per wave
    constexpr int TPB = 4 / WSPLIT;      // row-tiles per block

    __shared__ float lds_s[TPB][16][H];
    __shared__ float lds_t[TPB][16][H];

    const int w    = threadIdx.x >> 6;
    const int lane = threadIdx.x & 63;
    const int tile = w / WSPLIT;
    const int sub  = w % WSPLIT;
    const int pb   = sub * NTW;          // first panel of this wave
    const int mbase = (bix * TPB + tile) * 16;
    const int r = lane & 15;
    const int q = lane >> 4;

    f32x4 acc[NTW];
#pragma unroll
    for (int nn = 0; nn < NTW; ++nn) acc[nn] = (f32x4){0.f, 0.f, 0.f, 0.f};

    int arow = mbase + r;
    if (arow >= nrows) arow = nrows - 1;
    if (arow < 0) arow = 0;
    const unsigned short* xb = (const unsigned short*)Xv + (size_t)arow * K;
    const float* xf = (const float*)Xv + (size_t)arow * K;

#pragma unroll 2
    for (int k0 = 0; k0 < K; k0 += 32) {
        const int kk = k0 + q * 8;
        const unsigned kc = (unsigned)(kk >> 3);
        s16x8 a;
        if constexpr (ABF) {
            a = *reinterpret_cast<const s16x8*>(xb + kk);
        } else {
            float4 lo = *reinterpret_cast<const float4*>(xf + kk);
            float4 hi = *reinterpret_cast<const float4*>(xf + kk + 4);
            a[0] = (short)f2bf(lo.x); a[1] = (short)f2bf(lo.y);
            a[2] = (short)f2bf(lo.z); a[3] = (short)f2bf(lo.w);
            a[4] = (short)f2bf(hi.x); a[5] = (short)f2bf(hi.y);
            a[6] = (short)f2bf(hi.z); a[7] = (short)f2bf(hi.w);
        }
#pragma unroll
        for (int nn = 0; nn < NTW; ++nn) {
            const unsigned gn = (unsigned)(pb + nn);
            s16x8 b = *reinterpret_cast<const s16x8*>(Wt + ((gn * (K / 8) + kc) * 16 + (unsigned)r) * 8);
            acc[nn] = __builtin_amdgcn_mfma_f32_16x16x32_bf16(a, b, acc[nn], 0, 0, 0);
        }
    }

    // C store
#pragma unroll
    for (int nn = 0; nn < NTW; ++nn) {
        int col = (pb + nn) * 16 + r;
        if (col < F) {
#pragma unroll
            for (int i = 0; i < 4; ++i) {
                int row = mbase + q * 4 + i;
                if (row < nrows) C[(size_t)row * CS + col] = f2bf(acc[nn][i]);
            }
        }
    }

    // fused s/t partials: head-LOCAL arrays (NHW slots)
    float ps[4][NHW], pt[4][NHW];
#pragma unroll
    for (int i = 0; i < 4; ++i)
#pragma unroll
        for (int lh = 0; lh < NHW; ++lh) { ps[i][lh] = 0.f; pt[i][lh] = 0.f; }
    const int h_lo = (sub * NTW * 16) / D;   // wave-uniform
#pragma unroll
    for (int ss = 0; ss < WSPLIT; ++ss) {
        if (ss != sub) continue;   // wave-uniform branch
#pragma unroll
        for (int nn = 0; nn < NTW; ++nn) {
            const int gn = ss * NTW + nn;                       // compile-time
            const int col = gn * 16 + r;
            const int lh = (gn * 16) / D - (ss * NTW * 16) / D; // compile-time, < NHW
            float av = (col < F) ? asf[col] : 0.f;
            float dv = (col < F) ? adf[col] : 0.f;
#pragma unroll
            for (int i = 0; i < 4; ++i) {
                ps[i][lh] = fmaf(acc[nn][i], av, ps[i][lh]);
                pt[i][lh] = fmaf(acc[nn][i], dv, pt[i][lh]);
            }
        }
    }
#pragma unroll
    for (int off = 1; off <= 8; off <<= 1) {
#pragma unroll
        for (int i = 0; i < 4; ++i)
#pragma unroll
            for (int lh = 0; lh < NHW; ++lh) {
                ps[i][lh] += __shfl_xor(ps[i][lh], off);
                pt[i][lh] += __shfl_xor(pt[i][lh], off);
            }
    }

    // cross-wave reduce via LDS atomics
    constexpr int NE = TPB * 16 * H;
    if ((int)threadIdx.x < NE) {
        int idx = threadIdx.x;
        int t2 = idx / (16 * H), rem = idx % (16 * H);
        lds_s[t2][rem / H][rem % H] = 0.f;
        lds_t[t2][rem / H][rem % H] = 0.f;
    }
    __syncthreads();
#pragma unroll
    for (int lh = 0; lh < NHW; ++lh) {
        const int gh = h_lo + lh;   // wave-uniform
        if (gh < H && r == gh) {
#pragma unroll
            for (int i = 0; i < 4; ++i) {
                atomicAdd(&lds_s[tile][q * 4 + i][gh], ps[i][lh]);
                atomicAdd(&lds_t[tile][q * 4 + i][gh], pt[i][lh]);
            }
        }
    }
    __syncthreads();
    if ((int)threadIdx.x < NE) {
        int idx = threadIdx.x;
        int t2 = idx / (16 * H), rem = idx % (16 * H);
        int rw = rem / H, hh = rem % H;
        int row = bix * TPB * 16 + t2 * 16 + rw;
        if (row < nrows) {
            sbuf[row * SPAD + hh] = lds_s[t2][rw][hh];
            tbuf[row * H + hh]    = lds_t[t2][rw][hh];
        }
    }
}

// ---------------- shared gather core: fused segment-softmax + weighted gather over ELL ----------------
// acc[c] = sum_e p_e * feat[src][ch0+c];  returns z = sum_e p_e.  s from embedded row tail (SOFF>0) or sb.

template<int H, int D, int FS, int CPL, int SPAD, int SOFF>
__device__ __forceinline__ float gat_gather(const unsigned short* __restrict__ feat,
                                            const float* __restrict__ sb, const float* __restrict__ tb,
                                            const int* __restrict__ counts, const unsigned short* __restrict__ ell,
                                            int node, int lane, float (&acc)[CPL]) {
    constexpr int F = H * D;
    constexpr int NL = F / CPL;
    const unsigned short* __restrict__ ellp = ell + (size_t)node * ELLW;
    int cnt = counts[node];
    if (cnt > ELLW) cnt = ELLW;
    const bool act = lane < NL;
    const unsigned ch0 = (unsigned)(act ? lane : 0) * CPL;
    const int h = (int)(ch0 / D);
    const float th = tb[node * H + h];

    float z = 0.f;
#pragma unroll
    for (int c = 0; c < CPL; ++c) acc[c] = 0.f;

    auto pval = [&](float sv) -> float {
        float e = sv + th;
        e = fmaxf(e, NEG_SLOPE * e);
        return __expf(e);
    };
    auto sval = [&](unsigned b, unsigned i) -> float {
        if constexpr (SOFF > 0) {
            return *reinterpret_cast<const float*>(feat + b + SOFF + 2 * h);
        } else {
            (void)b;
            return sb[i * SPAD + h];
        }
    };
    auto fmae = [&](float p, const unsigned short* fp) {
        if constexpr (CPL == 4) {
            uint2 wq = *reinterpret_cast<const uint2*>(fp);
            acc[0] = fmaf(p, plo32(wq.x), acc[0]);
            acc[1] = fmaf(p, phi32(wq.x), acc[1]);
            acc[2] = fmaf(p, plo32(wq.y), acc[2]);
            acc[3] = fmaf(p, phi32(wq.y), acc[3]);
        } else if constexpr (CPL == 2) {
            unsigned wq = *reinterpret_cast<const unsigned*>(fp);
            acc[0] = fmaf(p, plo32(wq), acc[0]);
            acc[1] = fmaf(p, phi32(wq), acc[1]);
        } else {
            acc[0] = fmaf(p, bf2f(*fp), acc[0]);
        }
    };

    int j = 0;
    for (; j + 7 < cnt; j += 8) {
        uint4 iv = *reinterpret_cast<const uint4*>(ellp + j);
        unsigned i0 = iv.x & 0xffffu, i1 = iv.x >> 16;
        unsigned i2 = iv.y & 0xffffu, i3 = iv.y >> 16;
        unsigned i4 = iv.z & 0xffffu, i5 = iv.z >> 16;
        unsigned i6 = iv.w & 0xffffu, i7 = iv.w >> 16;
        unsigned b0 = i0 * FS, b1 = i1 * FS, b2 = i2 * FS, b3 = i3 * FS;
        unsigned b4 = i4 * FS, b5 = i5 * FS, b6 = i6 * FS, b7 = i7 * FS;
        if (act) {
            float s0 = sval(b0, i0);
            float s1 = sval(b1, i1);
            float s2 = sval(b2, i2);
            float s3 = sval(b3, i3);
            float s4 = sval(b4, i4);
            float s5 = sval(b5, i5);
            float s6 = sval(b6, i6);
            float s7 = sval(b7, i7);
            float p0 = pval(s0), p1 = pval(s1), p2 = pval(s2), p3 = pval(s3);
            float p4 = pval(s4), p5 = pval(s5), p6 = pval(s6), p7 = pval(s7);
            z += ((p0 + p1) + (p2 + p3)) + ((p4 + p5) + (p6 + p7));
            fmae(p0, feat + b0 + ch0);
            fmae(p1, feat + b1 + ch0);
            fmae(p2, feat + b2 + ch0);
            fmae(p3, feat + b3 + ch0);
            fmae(p4, feat + b4 + ch0);
            fmae(p5, feat + b5 + ch0);
            fmae(p6, feat + b6 + ch0);
            fmae(p7, feat + b7 + ch0);
        }
    }
    for (; j + 3 < cnt; j += 4) {
        uint2 iv = *reinterpret_cast<const uint2*>(ellp + j);
        unsigned i0 = iv.x & 0xffffu, i1 = iv.x >> 16;
        unsigned i2 = iv.y & 0xffffu, i3 = iv.y >> 16;
        unsigned b0 = i0 * FS, b1 = i1 * FS, b2 = i2 * FS, b3 = i3 * FS;
        if (act) {
            float p0 = pval(sval(b0, i0));
            float p1 = pval(sval(b1, i1));
            float p2 = pval(sval(b2, i2));
            float p3 = pval(sval(b3, i3));
            z += (p0 + p1) + (p2 + p3);
            fmae(p0, feat + b0 + ch0);
            fmae(p1, feat + b1 + ch0);
            fmae(p2, feat + b2 + ch0);
            fmae(p3, feat + b3 + ch0);
        }
    }
    for (; j < cnt; ++j) {
        unsigned sn = ellp[j];
        unsigned b = sn * FS;
        if (act) {
            float p = pval(sval(b, sn));
            z += p;
            fmae(p, feat + b + ch0);
        }
    }
    return z;
}

// ---------------- aggmm: aggregation + LN/ELU + NEXT-layer GEMM + next s/t, one dispatch ----------------
// Block = 16 nodes (4 waves x 4 serial). Phase 1: gather+LN+ELU -> bf16 rows in LDS.
// Phase 2: 16-row MFMA vs Wt2 (panel-k-major), C2 store + embedded s2 + t2.

template<int H, int D, int FS, int CPL, int SPAD, int SOFF,            // gather input (layer N)
         int F2, int CS2, int FP2, int H2, int D2, int SOFF2>          // gemm output (layer N+1); K2 = H*D
__global__ __launch_bounds__(256, 4) void aggmm_kernel(const unsigned short* __restrict__ feat,
                                                       const float* __restrict__ sb, const float* __restrict__ tbin,
                                                       const int* __restrict__ counts, const unsigned short* __restrict__ ell,
                                                       const float* __restrict__ bias, const float* __restrict__ lnw,
                                                       const float* __restrict__ lnb,
                                                       const unsigned short* __restrict__ Wt2,
                                                       const float* __restrict__ asf2, const float* __restrict__ adf2,
                                                       unsigned short* __restrict__ C2, float* __restrict__ tbout,
                                                       int n) {
    constexpr int F   = H * D;     // = K2
    constexpr int NL  = F / CPL;
    constexpr int NT2 = FP2 / 16;
    constexpr int NP  = (NT2 + 3) / 4;   // max panels per wave

    __shared__ unsigned short arows[16][200];   // bf16 LN-ELU rows; stride 200 -> 2-way bank alias (free)
    __shared__ float lds_s[16][H2];
    __shared__ float lds_t[16][H2];

    const int wv   = threadIdx.x >> 6;
    const int lane = threadIdx.x & 63;
    const int r = lane & 15, q = lane >> 4;
    const int nb = (int)blockIdx.x * 16;
    (void)n;   // grid is exact: NNODES = 16 * gridDim

    if ((int)threadIdx.x < 16 * H2) {
        lds_s[threadIdx.x / H2][threadIdx.x % H2] = 0.f;
        lds_t[threadIdx.x / H2][threadIdx.x % H2] = 0.f;
    }

    const bool act = lane < NL;
    const unsigned ch0 = (unsigned)(act ? lane : 0) * CPL;

    // ---- phase 1: 4 nodes per wave, serial ----
    for (int u = 0; u < 4; ++u) {
        const int node = nb + wv * 4 + u;
        float acc[CPL];
        float z = gat_gather<H, D, FS, CPL, SPAD, SOFF>(feat, sb, tbin, counts, ell, node, lane, acc);

        const float zinv = 1.f / (z + 1e-16f);
        float v[CPL];
        float sum = 0.f, sumsq = 0.f;
#pragma unroll
        for (int c = 0; c < CPL; ++c) v[c] = 0.f;
        if (act) {
#pragma unroll
            for (int c = 0; c < CPL; ++c) {
                v[c] = fmaf(acc[c], zinv, bias[ch0 + c]);
                sum += v[c];
                sumsq += v[c] * v[c];
            }
        }
#pragma unroll
        for (int off = 32; off; off >>= 1) {
            sum += __shfl_xor(sum, off);
            sumsq += __shfl_xor(sumsq, off);
        }
        const float mu = sum / F;
        const float var = sumsq / F - mu * mu;
        const float rstd = rsqrtf(var + LN_EPS);
        if (act) {
            unsigned short yb[CPL];
#pragma unroll
            for (int c = 0; c < CPL; ++c) {
                float y = (v[c] - mu) * rstd * lnw[ch0 + c] + lnb[ch0 + c];
                y = y > 0.f ? y : expm1f(y);  // ELU
                yb[c] = f2bf(y);
            }
            unsigned short* rp = &arows[wv * 4 + u][ch0];
            if constexpr (CPL == 4) {
                ushort4 st = {yb[0], yb[1], yb[2], yb[3]};
                *reinterpret_cast<ushort4*>(rp) = st;
            } else if constexpr (CPL == 2) {
                ushort2 st = {yb[0], yb[1]};
                *reinterpret_cast<ushort2*>(rp) = st;
            } else {
                *rp = yb[0];
            }
        }
    }
    __syncthreads();

    // ---- phase 2: MFMA 16 rows (LDS) x Wt2 -> C2 + s2/t2 ----
    f32x4 acc2[NP];
#pragma unroll
    for (int pi = 0; pi < NP; ++pi) acc2[pi] = (f32x4){0.f, 0.f, 0.f, 0.f};

#pragma unroll 2
    for (int k0 = 0; k0 < F; k0 += 32) {
        const int kk = k0 + q * 8;
        const unsigned kc = (unsigned)(kk >> 3);
        s16x8 a = *reinterpret_cast<const s16x8*>(&arows[r][kk]);
#pragma unroll
        for (int pi = 0; pi < NP; ++pi) {
            const int gn = wv + 4 * pi;
            if (gn < NT2) {
                s16x8 b = *reinterpret_cast<const s16x8*>(Wt2 + (((unsigned)gn * (F / 8) + kc) * 16 + (unsigned)r) * 8);
                acc2[pi] = __builtin_amdgcn_mfma_f32_16x16x32_bf16(a, b, acc2[pi], 0, 0, 0);
            }
        }
    }

    float ps[4][NP], pt[4][NP];
#pragma unroll
    for (int i = 0; i < 4; ++i)
#pragma unroll
        for (int pi = 0; pi < NP; ++pi) { ps[i][pi] = 0.f; pt[i][pi] = 0.f; }

#pragma unroll
    for (int pi = 0; pi < NP; ++pi) {
        const int gn = wv + 4 * pi;
        if (gn < NT2) {
            const int col = gn * 16 + r;
            const float av = (col < F2) ? asf2[col] : 0.f;
            const float dv = (col < F2) ? adf2[col] : 0.f;
            if (col < F2) {
#pragma unroll
                for (int i = 0; i < 4; ++i)
                    C2[(size_t)(nb + q * 4 + i) * CS2 + col] = f2bf(acc2[pi][i]);
            }
#pragma unroll
            for (int i = 0; i < 4; ++i) {
                ps[i][pi] = acc2[pi][i] * av;
                pt[i][pi] = acc2[pi][i] * dv;
            }
        }
    }
#pragma unroll
    for (int off = 1; off <= 8; off <<= 1) {
#pragma unroll
        for (int i = 0; i < 4; ++i)
#pragma unroll
            for (int pi = 0; pi < NP; ++pi) {
                ps[i][pi] += __shfl_xor(ps[i][pi], off);
                pt[i][pi] += __shfl_xor(pt[i][pi], off);
            }
    }
    if (r == 0) {
#pragma unroll
        for (int pi = 0; pi < NP; ++pi) {
            const int gn = wv + 4 * pi;
            if (gn < NT2) {
                const int gh = (gn * 16) / D2;   // wave-uniform
#pragma unroll
                for (int i = 0; i < 4; ++i) {
                    atomicAdd(&lds_s[q * 4 + i][gh], ps[i][pi]);
                    atomicAdd(&lds_t[q * 4 + i][gh], pt[i][pi]);
                }
            }
        }
    }
    __syncthreads();
    if ((int)threadIdx.x < 16 * H2) {
        int ln = threadIdx.x / H2, hh = threadIdx.x % H2;
        int node = nb + ln;
        *reinterpret_cast<float*>(C2 + (size_t)node * CS2 + SOFF2 + 2 * hh) = lds_s[ln][hh];
        tbout[node * H2 + hh] = lds_t[ln][hh];
    }
}

// ---------------- final aggregation: LN + log_softmax (layer 3 output) ----------------

template<int H, int D, int FS, int CPL, int SPAD, int SOFF>
__global__ __launch_bounds__(256) void aggfin_kernel(const unsigned short* __restrict__ feat,
                                                     const float* __restrict__ sb, const float* __restrict__ tb,
                                                     const int* __restrict__ counts, const unsigned short* __restrict__ ell,
                                                     const float* __restrict__ bias, const float* __restrict__ lnw,
                                                     const float* __restrict__ lnb, float* __restrict__ out, int n) {
    constexpr int F = H * D;
    constexpr int NL = F / CPL;
    int wid = (blockIdx.x * blockDim.x + threadIdx.x) >> 6;
    int lane = threadIdx.x & 63;
    if (wid >= n) return;
    const int node = wid;
    const bool act = lane < NL;
    const unsigned ch0 = (unsigned)(act ? lane : 0) * CPL;

    float acc[CPL];
    float z = gat_gather<H, D, FS, CPL, SPAD, SOFF>(feat, sb, tb, counts, ell, node, lane, acc);

    const float zinv = 1.f / (z + 1e-16f);
    float v = 0.f, sum = 0.f, sumsq = 0.f;
    if (act) {
        v = fmaf(acc[0], zinv, bias[ch0]);
        sum = v;
        sumsq = v * v;
    }
#pragma unroll
    for (int off = 32; off; off >>= 1) {
        sum += __shfl_xor(sum, off);
        sumsq += __shfl_xor(sumsq, off);
    }
    const float mu = sum / F;
    const float var = sumsq / F - mu * mu;
    const float rstd = rsqrtf(var + LN_EPS);

    float y = 0.f, mx = -1e30f;
    if (act) {
        y = (v - mu) * rstd * lnw[ch0] + lnb[ch0];
        mx = y;
    }
#pragma unroll
    for (int off = 32; off; off >>= 1) mx = fmaxf(mx, __shfl_xor(mx, off));
    float se = act ? __expf(y - mx) : 0.f;
#pragma unroll
    for (int off = 32; off; off >>= 1) se += __shfl_xor(se, off);
    float lse = logf(se);
    if (act) out[(size_t)node * F + ch0] = y - mx - lse;
}

// ---------------- host launch ----------------

static inline size_t align_up(size_t x) { return (x + 255) & ~(size_t)255; }

extern "C" void kernel_launch(void* const* d_in, const int* in_sizes, int n_in,
                              void* d_out, int out_size, void* d_ws, size_t ws_size,
                              hipStream_t stream) {
    const float* x    = (const float*)d_in[0];
    const int*   eidx = (const int*)d_in[1];
    const float* W1   = (const float*)d_in[2];
    const float* a1s  = (const float*)d_in[3];
    const float* a1d  = (const float*)d_in[4];
    const float* b1   = (const float*)d_in[5];
    const float* ln1w = (const float*)d_in[6];
    const float* ln1b = (const float*)d_in[7];
    const float* W2   = (const float*)d_in[8];
    const float* a2s  = (const float*)d_in[9];
    const float* a2d  = (const float*)d_in[10];
    const float* b2   = (const float*)d_in[11];
    const float* ln2w = (const float*)d_in[12];
    const float* ln2b = (const float*)d_in[13];
    const float* W3   = (const float*)d_in[14];
    const float* a3s  = (const float*)d_in[15];
    const float* a3d  = (const float*)d_in[16];
    const float* b3   = (const float*)d_in[17];
    const float* ln3w = (const float*)d_in[18];
    const float* ln3b = (const float*)d_in[19];

    char* w = (char*)d_ws;
    int* counts = (int*)w;  w += align_up((size_t)NNODES * 4);
    unsigned short* ell = (unsigned short*)w;  w += align_up((size_t)NNODES * ELLW * 2);
    unsigned short* bufA = (unsigned short*)w; w += align_up((size_t)NNODES * 192 * 2);
    unsigned short* bufB = (unsigned short*)w; w += align_up((size_t)NNODES * 128 * 2);
    float* sbuf  = (float*)w; w += align_up((size_t)NNODES * 8 * 4);
    float* tbufA = (float*)w; w += align_up((size_t)NNODES * 6 * 4);
    float* tbufB = (float*)w; w += align_up((size_t)NNODES * 6 * 4);
    unsigned short* wt1 = (unsigned short*)w; w += align_up((size_t)W1SZ * 2);
    unsigned short* wt2 = (unsigned short*)w; w += align_up((size_t)W2SZ * 2);
    unsigned short* wt3 = (unsigned short*)w; w += align_up((size_t)W3SZ * 2);

    const int BS = 256;
    const int PREP_N = W1SZ + W2SZ + W3SZ;   // 72192 > NNODES, covers counts/ELL init too
    prep_kernel<<<(PREP_N + BS - 1) / BS, BS, 0, stream>>>(W1, W2, W3, wt1, wt2, wt3, counts, ell);

    const int G1 = NNODES / 16;               // 3125 gemm blocks (1 row-tile/block, WSPLIT=4)
    const int FILL_NB  = (NEDGES + BS - 1) / BS;  // 3125 edge blocks (appended)
    const int GRID_AMM = NNODES / 16;         // 3125 blocks, 16 nodes each (exact)
    const int GRID_AGG = (NNODES + 3) / 4;

    // ---- layer 1 GEMM: 256 -> F=192 (stride 192) + fused s/t + ELL fill ----
    gemmst_kernel<256, 192, 192, 192, 6, 32, 8, 4, 2, false, true>
        <<<G1 + FILL_NB, BS, 0, stream>>>(x, wt1, bufA, a1s, a1d, sbuf, tbufA, NNODES,
                                          G1, eidx, counts, ell, NEDGES);

    // ---- agg L1 (H=6,D=32, s in sbuf) + LN1/ELU + GEMM L2 (192->96, stride 128, s2 emb @96) + s2/t2 ----
    aggmm_kernel<6, 32, 192, 4, 8, 0,   96, 128, 96, 3, 32, 96>
        <<<GRID_AMM, BS, 0, stream>>>(bufA, sbuf, tbufA, counts, ell, b1, ln1w, ln1b,
                                      wt2, a2s, a2d, bufB, tbufB, NNODES);

    // ---- agg L2 (H=3,D=32, s emb @96) + LN2/ELU + GEMM L3 (96->40, stride 64, s3 emb @40) + s3/t3 ----
    aggmm_kernel<3, 32, 128, 2, 4, 96,  40, 64, 48, 1, 40, 40>
        <<<GRID_AMM, BS, 0, stream>>>(bufB, sbuf, tbufB, counts, ell, b2, ln2w, ln2b,
                                      wt3, a3s, a3d, bufA, tbufA, NNODES);

    // ---- final agg (H=1,D=40, s emb @40) + LN3 + log_softmax ----
    aggfin_kernel<1, 40, 64, 1, 1, 40>
        <<<GRID_AGG, BS, 0, stream>>>(bufA, sbuf, tbufA, counts, ell, b3, ln3w, ln3b, (float*)d_out, NNODES);
}

// Round 11
// 260.231 us; speedup vs baseline: 1.0322x; 1.0322x over previous
//
#include <hip/hip_runtime.h>
#include <hip/hip_bf16.h>
#include <cstdint>

#define NNODES 50000
#define NEDGES 800000
#define ETOT   (NEDGES + NNODES)
#define LN_EPS 1e-5f
#define NEG_SLOPE 0.2f
#define ELLW   64   // ELL row width (128B line); slot0 = self-loop

typedef __attribute__((ext_vector_type(8))) short s16x8;
typedef __attribute__((ext_vector_type(4))) float f32x4;

__device__ __forceinline__ float bf2f(unsigned short u) {
    return __uint_as_float(((unsigned int)u) << 16);
}
__device__ __forceinline__ unsigned short f2bf(float f) {
    unsigned int u = __float_as_uint(f);
    u += 0x7FFFu + ((u >> 16) & 1u);   // round-to-nearest-even
    return (unsigned short)(u >> 16);
}
// unpack packed bf16x2 dword -> f32
__device__ __forceinline__ float plo32(unsigned u) { return __uint_as_float(u << 16); }
__device__ __forceinline__ float phi32(unsigned u) { return __uint_as_float(u & 0xffff0000u); }

// ---------------- prep: W -> bf16 panel-k-major tiles + counts/ELL init ----------------

#define W1SZ (192 * 256)
#define W2SZ (96 * 192)
#define W3SZ (48 * 96)

__global__ __launch_bounds__(256) void prep_kernel(const float* __restrict__ W1, const float* __restrict__ W2,
                                                   const float* __restrict__ W3, unsigned short* __restrict__ wt1,
                                                   unsigned short* __restrict__ wt2, unsigned short* __restrict__ wt3,
                                                   int* __restrict__ counts, unsigned short* __restrict__ ell) {
    int i = blockIdx.x * 256 + threadIdx.x;
    if (i < NNODES) {
        counts[i] = 1;                               // self-loop occupies slot 0
        ell[(size_t)i * ELLW] = (unsigned short)i;
    }
    if (i < W1SZ) {
        int c = i >> 8, k = i & 255;              // c: out-col 0..191, k: in 0..255
        int n = c >> 4, r = c & 15;
        wt1[((n * 32 + (k >> 3)) * 16 + r) * 8 + (k & 7)] = f2bf(W1[k * 192 + c]);
    } else if (i < W1SZ + W2SZ) {
        int j = i - W1SZ;
        int c = j / 192, k = j - c * 192;         // c 0..95, k 0..191
        int n = c >> 4, r = c & 15;
        wt2[((n * 24 + (k >> 3)) * 16 + r) * 8 + (k & 7)] = f2bf(W2[k * 96 + c]);
    } else if (i < W1SZ + W2SZ + W3SZ) {
        int j = i - (W1SZ + W2SZ);
        int c = j / 96, k = j - c * 96;           // c 0..47 (padded), k 0..95
        int n = c >> 4, r = c & 15;
        wt3[((n * 12 + (k >> 3)) * 16 + r) * 8 + (k & 7)] = (c < 40) ? f2bf(W3[k * 40 + c]) : (unsigned short)0;
    }
}

// ---------------- MFMA GEMM (F-split across waves) + fused s/t (+ ELL fill appended last) ----------------
// SEMB: embed s[row][h] as float at short-offset F+2h inside the C row (tail bytes of an
// already-fetched cache line) so the aggregation gather gets s for free.

template<int K, int F, int CS, int FP, int H, int D, int SPAD, int WSPLIT, int NHW, bool ABF, bool FILL, bool SEMB>
__global__ __launch_bounds__(256, 4) void gemmst_kernel(const void* __restrict__ Xv,
                                                        const unsigned short* __restrict__ Wt,
                                                        unsigned short* __restrict__ C,
                                                        const float* __restrict__ asf, const float* __restrict__ adf,
                                                        float* __restrict__ sbuf, float* __restrict__ tbuf,
                                                        int nrows, int gblocks,
                                                        const int* __restrict__ eidx, int* counts,
                                                        unsigned short* __restrict__ ell, int e) {
    if constexpr (FILL) {
        if (blockIdx.x >= (unsigned)gblocks) {   // fill blocks appended last (best measured, R6)
            int i = ((int)blockIdx.x - gblocks) * 256 + (int)threadIdx.x;
            if (i < e) {
                int sv = eidx[i];
                int d  = eidx[e + i];
                int slot = atomicAdd(&counts[d], 1);
                if (slot < ELLW) ell[(size_t)d * ELLW + slot] = (unsigned short)sv;
            }
            return;
        }
    }
    const int bix = (int)blockIdx.x;

    constexpr int NT  = FP / 16;
    constexpr int NTW = NT / WSPLIT;     // panels per wave
    constexpr int TPB = 4 / WSPLIT;      // row-tiles per block

    __shared__ float lds_s[TPB][16][H];
    __shared__ float lds_t[TPB][16][H];

    const int w    = threadIdx.x >> 6;
    const int lane = threadIdx.x & 63;
    const int tile = w / WSPLIT;
    const int sub  = w % WSPLIT;
    const int pb   = sub * NTW;          // first panel of this wave
    const int mbase = (bix * TPB + tile) * 16;
    const int r = lane & 15;
    const int q = lane >> 4;

    if constexpr (WSPLIT == 1) {
        if (mbase >= nrows) return;      // independent waves, no barrier in this path
    }

    f32x4 acc[NTW];
#pragma unroll
    for (int nn = 0; nn < NTW; ++nn) acc[nn] = (f32x4){0.f, 0.f, 0.f, 0.f};

    int arow = mbase + r;
    if (arow >= nrows) arow = nrows - 1;
    if (arow < 0) arow = 0;
    const unsigned short* xb = (const unsigned short*)Xv + (size_t)arow * K;
    const float* xf = (const float*)Xv + (size_t)arow * K;

#pragma unroll 2
    for (int k0 = 0; k0 < K; k0 += 32) {
        const int kk = k0 + q * 8;
        const unsigned kc = (unsigned)(kk >> 3);
        s16x8 a;
        if constexpr (ABF) {
            a = *reinterpret_cast<const s16x8*>(xb + kk);
        } else {
            float4 lo = *reinterpret_cast<const float4*>(xf + kk);
            float4 hi = *reinterpret_cast<const float4*>(xf + kk + 4);
            a[0] = (short)f2bf(lo.x); a[1] = (short)f2bf(lo.y);
            a[2] = (short)f2bf(lo.z); a[3] = (short)f2bf(lo.w);
            a[4] = (short)f2bf(hi.x); a[5] = (short)f2bf(hi.y);
            a[6] = (short)f2bf(hi.z); a[7] = (short)f2bf(hi.w);
        }
#pragma unroll
        for (int nn = 0; nn < NTW; ++nn) {
            const unsigned gn = (unsigned)(pb + nn);
            s16x8 b = *reinterpret_cast<const s16x8*>(Wt + ((gn * (K / 8) + kc) * 16 + (unsigned)r) * 8);
            acc[nn] = __builtin_amdgcn_mfma_f32_16x16x32_bf16(a, b, acc[nn], 0, 0, 0);
        }
    }

    // C store
#pragma unroll
    for (int nn = 0; nn < NTW; ++nn) {
        int col = (pb + nn) * 16 + r;
        if (col < F) {
#pragma unroll
            for (int i = 0; i < 4; ++i) {
                int row = mbase + q * 4 + i;
                if (row < nrows) C[(size_t)row * CS + col] = f2bf(acc[nn][i]);
            }
        }
    }

    // fused s/t partials: head-LOCAL arrays (NHW slots), compile-time lh in unrolled sub dispatch
    float ps[4][NHW], pt[4][NHW];
#pragma unroll
    for (int i = 0; i < 4; ++i)
#pragma unroll
        for (int lh = 0; lh < NHW; ++lh) { ps[i][lh] = 0.f; pt[i][lh] = 0.f; }
    const int h_lo = (sub * NTW * 16) / D;   // wave-uniform
#pragma unroll
    for (int ss = 0; ss < WSPLIT; ++ss) {
        if (ss != sub) continue;   // wave-uniform branch
#pragma unroll
        for (int nn = 0; nn < NTW; ++nn) {
            const int gn = ss * NTW + nn;                       // compile-time
            const int col = gn * 16 + r;
            const int lh = (gn * 16) / D - (ss * NTW * 16) / D; // compile-time, < NHW
            float av = (col < F) ? asf[col] : 0.f;
            float dv = (col < F) ? adf[col] : 0.f;
#pragma unroll
            for (int i = 0; i < 4; ++i) {
                ps[i][lh] = fmaf(acc[nn][i], av, ps[i][lh]);
                pt[i][lh] = fmaf(acc[nn][i], dv, pt[i][lh]);
            }
        }
    }
    // 16-lane xor tree within q-group
#pragma unroll
    for (int off = 1; off <= 8; off <<= 1) {
#pragma unroll
        for (int i = 0; i < 4; ++i)
#pragma unroll
            for (int lh = 0; lh < NHW; ++lh) {
                ps[i][lh] += __shfl_xor(ps[i][lh], off);
                pt[i][lh] += __shfl_xor(pt[i][lh], off);
            }
    }

    if constexpr (WSPLIT == 1) {
        // single wave owns all panels: direct store (NHW == H)
#pragma unroll
        for (int lh = 0; lh < NHW; ++lh) {
            const int gh = lh;   // h_lo == 0
            if (gh < H && r == gh) {
#pragma unroll
                for (int i = 0; i < 4; ++i) {
                    int row = mbase + q * 4 + i;
                    if (row < nrows) {
                        if constexpr (SEMB) {
                            reinterpret_cast<float*>(C + (size_t)row * CS + F)[gh] = ps[i][lh];
                        } else {
                            sbuf[row * SPAD + gh] = ps[i][lh];
                        }
                        tbuf[row * H + gh] = pt[i][lh];
                    }
                }
            }
        }
    } else {
        // cross-wave reduce via LDS atomics (boundary heads accumulate from two waves)
        constexpr int NE = TPB * 16 * H;
        if ((int)threadIdx.x < NE) {
            int idx = threadIdx.x;
            int t2 = idx / (16 * H), rem = idx % (16 * H);
            lds_s[t2][rem / H][rem % H] = 0.f;
            lds_t[t2][rem / H][rem % H] = 0.f;
        }
        __syncthreads();
#pragma unroll
        for (int lh = 0; lh < NHW; ++lh) {
            const int gh = h_lo + lh;   // wave-uniform
            if (gh < H && r == gh) {
#pragma unroll
                for (int i = 0; i < 4; ++i) {
                    atomicAdd(&lds_s[tile][q * 4 + i][gh], ps[i][lh]);
                    atomicAdd(&lds_t[tile][q * 4 + i][gh], pt[i][lh]);
                }
            }
        }
        __syncthreads();
        if ((int)threadIdx.x < NE) {
            int idx = threadIdx.x;
            int t2 = idx / (16 * H), rem = idx % (16 * H);
            int rw = rem / H, hh = rem % H;
            int row = bix * TPB * 16 + t2 * 16 + rw;
            if (row < nrows) {
                if constexpr (SEMB) {
                    reinterpret_cast<float*>(C + (size_t)row * CS + F)[hh] = lds_s[t2][rw][hh];
                } else {
                    sbuf[row * SPAD + hh] = lds_s[t2][rw][hh];
                }
                tbuf[row * H + hh] = pt[0][0] * 0.f + lds_t[t2][rw][hh];
            }
        }
    }
}

// ---------------- aggregation v10: fused segment-softmax + gather; s embedded in feat row (SOFF>0) ----------------
// out[i] = (sum_e exp(lrelu(s[src]+t[i])) * h[src]) / (sum_e exp(...)) ; max-subtraction cancels.

template<int H, int D, int FS, int CPL, int SPAD, int SOFF, int MODE, typename OutT>
__global__ __launch_bounds__(256) void agg10_kernel(const unsigned short* __restrict__ feat,
                                                    const float* __restrict__ sb, const float* __restrict__ tb,
                                                    const int* __restrict__ counts, const unsigned short* __restrict__ ell,
                                                    const float* __restrict__ bias, const float* __restrict__ lnw,
                                                    const float* __restrict__ lnb, OutT* __restrict__ out, int n) {
    constexpr int F = H * D;
    constexpr int NL = F / CPL;
    int wid = (blockIdx.x * blockDim.x + threadIdx.x) >> 6;
    int lane = threadIdx.x & 63;
    if (wid >= n) return;
    const int node = wid;
    const unsigned short* __restrict__ ellp = ell + (size_t)node * ELLW;
    int cnt = counts[node];
    if (cnt > ELLW) cnt = ELLW;
    const bool act = lane < NL;
    const unsigned ch0 = (unsigned)(lane < NL ? lane : 0) * CPL;
    const int h = (int)(ch0 / D);
    const float th = tb[node * H + h];

    float z = 0.f;
    float acc[CPL];
#pragma unroll
    for (int c = 0; c < CPL; ++c) acc[c] = 0.f;

    auto pval = [&](float sv) -> float {
        float e = sv + th;
        e = fmaxf(e, NEG_SLOPE * e);
        return __expf(e);
    };
    // s for source-node row base b (in shorts) / node id i
    auto sval = [&](unsigned b, unsigned i) -> float {
        if constexpr (SOFF > 0) {
            return *reinterpret_cast<const float*>(feat + b + SOFF + 2 * h);
        } else {
            (void)b;
            return sb[i * SPAD + h];
        }
    };
    auto fmae = [&](float p, const unsigned short* fp) {
        if constexpr (CPL == 4) {
            uint2 w = *reinterpret_cast<const uint2*>(fp);
            acc[0] = fmaf(p, plo32(w.x), acc[0]);
            acc[1] = fmaf(p, phi32(w.x), acc[1]);
            acc[2] = fmaf(p, plo32(w.y), acc[2]);
            acc[3] = fmaf(p, phi32(w.y), acc[3]);
        } else if constexpr (CPL == 2) {
            unsigned w = *reinterpret_cast<const unsigned*>(fp);
            acc[0] = fmaf(p, plo32(w), acc[0]);
            acc[1] = fmaf(p, phi32(w), acc[1]);
        } else {
            acc[0] = fmaf(p, bf2f(*fp), acc[0]);
        }
    };

    int j = 0;
    // 8-edge main loop: 8 ids in one uint4 (rows 128B-aligned)
    for (; j + 7 < cnt; j += 8) {
        uint4 iv = *reinterpret_cast<const uint4*>(ellp + j);
        unsigned i0 = iv.x & 0xffffu, i1 = iv.x >> 16;
        unsigned i2 = iv.y & 0xffffu, i3 = iv.y >> 16;
        unsigned i4 = iv.z & 0xffffu, i5 = iv.z >> 16;
        unsigned i6 = iv.w & 0xffffu, i7 = iv.w >> 16;
        unsigned b0 = i0 * FS, b1 = i1 * FS, b2 = i2 * FS, b3 = i3 * FS;
        unsigned b4 = i4 * FS, b5 = i5 * FS, b6 = i6 * FS, b7 = i7 * FS;
        if (act) {
            float s0 = sval(b0, i0);
            float s1 = sval(b1, i1);
            float s2 = sval(b2, i2);
            float s3 = sval(b3, i3);
            float s4 = sval(b4, i4);
            float s5 = sval(b5, i5);
            float s6 = sval(b6, i6);
            float s7 = sval(b7, i7);
            if constexpr (CPL == 4) {
                uint2 w0 = *reinterpret_cast<const uint2*>(feat + b0 + ch0);
                uint2 w1 = *reinterpret_cast<const uint2*>(feat + b1 + ch0);
                uint2 w2 = *reinterpret_cast<const uint2*>(feat + b2 + ch0);
                uint2 w3 = *reinterpret_cast<const uint2*>(feat + b3 + ch0);
                uint2 w4 = *reinterpret_cast<const uint2*>(feat + b4 + ch0);
                uint2 w5 = *reinterpret_cast<const uint2*>(feat + b5 + ch0);
                uint2 w6 = *reinterpret_cast<const uint2*>(feat + b6 + ch0);
                uint2 w7 = *reinterpret_cast<const uint2*>(feat + b7 + ch0);
                float p0 = pval(s0), p1 = pval(s1), p2 = pval(s2), p3 = pval(s3);
                float p4 = pval(s4), p5 = pval(s5), p6 = pval(s6), p7 = pval(s7);
                z += ((p0 + p1) + (p2 + p3)) + ((p4 + p5) + (p6 + p7));
                acc[0] = fmaf(p0, plo32(w0.x), acc[0]); acc[1] = fmaf(p0, phi32(w0.x), acc[1]);
                acc[2] = fmaf(p0, plo32(w0.y), acc[2]); acc[3] = fmaf(p0, phi32(w0.y), acc[3]);
                acc[0] = fmaf(p1, plo32(w1.x), acc[0]); acc[1] = fmaf(p1, phi32(w1.x), acc[1]);
                acc[2] = fmaf(p1, plo32(w1.y), acc[2]); acc[3] = fmaf(p1, phi32(w1.y), acc[3]);
                acc[0] = fmaf(p2, plo32(w2.x), acc[0]); acc[1] = fmaf(p2, phi32(w2.x), acc[1]);
                acc[2] = fmaf(p2, plo32(w2.y), acc[2]); acc[3] = fmaf(p2, phi32(w2.y), acc[3]);
                acc[0] = fmaf(p3, plo32(w3.x), acc[0]); acc[1] = fmaf(p3, phi32(w3.x), acc[1]);
                acc[2] = fmaf(p3, plo32(w3.y), acc[2]); acc[3] = fmaf(p3, phi32(w3.y), acc[3]);
                acc[0] = fmaf(p4, plo32(w4.x), acc[0]); acc[1] = fmaf(p4, phi32(w4.x), acc[1]);
                acc[2] = fmaf(p4, plo32(w4.y), acc[2]); acc[3] = fmaf(p4, phi32(w4.y), acc[3]);
                acc[0] = fmaf(p5, plo32(w5.x), acc[0]); acc[1] = fmaf(p5, phi32(w5.x), acc[1]);
                acc[2] = fmaf(p5, plo32(w5.y), acc[2]); acc[3] = fmaf(p5, phi32(w5.y), acc[3]);
                acc[0] = fmaf(p6, plo32(w6.x), acc[0]); acc[1] = fmaf(p6, phi32(w6.x), acc[1]);
                acc[2] = fmaf(p6, plo32(w6.y), acc[2]); acc[3] = fmaf(p6, phi32(w6.y), acc[3]);
                acc[0] = fmaf(p7, plo32(w7.x), acc[0]); acc[1] = fmaf(p7, phi32(w7.x), acc[1]);
                acc[2] = fmaf(p7, plo32(w7.y), acc[2]); acc[3] = fmaf(p7, phi32(w7.y), acc[3]);
            } else if constexpr (CPL == 2) {
                unsigned w0 = *reinterpret_cast<const unsigned*>(feat + b0 + ch0);
                unsigned w1 = *reinterpret_cast<const unsigned*>(feat + b1 + ch0);
                unsigned w2 = *reinterpret_cast<const unsigned*>(feat + b2 + ch0);
                unsigned w3 = *reinterpret_cast<const unsigned*>(feat + b3 + ch0);
                unsigned w4 = *reinterpret_cast<const unsigned*>(feat + b4 + ch0);
                unsigned w5 = *reinterpret_cast<const unsigned*>(feat + b5 + ch0);
                unsigned w6 = *reinterpret_cast<const unsigned*>(feat + b6 + ch0);
                unsigned w7 = *reinterpret_cast<const unsigned*>(feat + b7 + ch0);
                float p0 = pval(s0), p1 = pval(s1), p2 = pval(s2), p3 = pval(s3);
                float p4 = pval(s4), p5 = pval(s5), p6 = pval(s6), p7 = pval(s7);
                z += ((p0 + p1) + (p2 + p3)) + ((p4 + p5) + (p6 + p7));
                acc[0] = fmaf(p0, plo32(w0), acc[0]); acc[1] = fmaf(p0, phi32(w0), acc[1]);
                acc[0] = fmaf(p1, plo32(w1), acc[0]); acc[1] = fmaf(p1, phi32(w1), acc[1]);
                acc[0] = fmaf(p2, plo32(w2), acc[0]); acc[1] = fmaf(p2, phi32(w2), acc[1]);
                acc[0] = fmaf(p3, plo32(w3), acc[0]); acc[1] = fmaf(p3, phi32(w3), acc[1]);
                acc[0] = fmaf(p4, plo32(w4), acc[0]); acc[1] = fmaf(p4, phi32(w4), acc[1]);
                acc[0] = fmaf(p5, plo32(w5), acc[0]); acc[1] = fmaf(p5, phi32(w5), acc[1]);
                acc[0] = fmaf(p6, plo32(w6), acc[0]); acc[1] = fmaf(p6, phi32(w6), acc[1]);
                acc[0] = fmaf(p7, plo32(w7), acc[0]); acc[1] = fmaf(p7, phi32(w7), acc[1]);
            } else {
                unsigned short w0 = feat[b0 + ch0], w1 = feat[b1 + ch0], w2 = feat[b2 + ch0], w3 = feat[b3 + ch0];
                unsigned short w4 = feat[b4 + ch0], w5 = feat[b5 + ch0], w6 = feat[b6 + ch0], w7 = feat[b7 + ch0];
                float p0 = pval(s0), p1 = pval(s1), p2 = pval(s2), p3 = pval(s3);
                float p4 = pval(s4), p5 = pval(s5), p6 = pval(s6), p7 = pval(s7);
                z += ((p0 + p1) + (p2 + p3)) + ((p4 + p5) + (p6 + p7));
                acc[0] = fmaf(p0, bf2f(w0), acc[0]);
                acc[0] = fmaf(p1, bf2f(w1), acc[0]);
                acc[0] = fmaf(p2, bf2f(w2), acc[0]);
                acc[0] = fmaf(p3, bf2f(w3), acc[0]);
                acc[0] = fmaf(p4, bf2f(w4), acc[0]);
                acc[0] = fmaf(p5, bf2f(w5), acc[0]);
                acc[0] = fmaf(p6, bf2f(w6), acc[0]);
                acc[0] = fmaf(p7, bf2f(w7), acc[0]);
            }
        }
    }
    // 4-edge block
    for (; j + 3 < cnt; j += 4) {
        uint2 iv = *reinterpret_cast<const uint2*>(ellp + j);
        unsigned i0 = iv.x & 0xffffu, i1 = iv.x >> 16;
        unsigned i2 = iv.y & 0xffffu, i3 = iv.y >> 16;
        unsigned b0 = i0 * FS, b1 = i1 * FS, b2 = i2 * FS, b3 = i3 * FS;
        if (act) {
            float p0 = pval(sval(b0, i0));
            float p1 = pval(sval(b1, i1));
            float p2 = pval(sval(b2, i2));
            float p3 = pval(sval(b3, i3));
            z += (p0 + p1) + (p2 + p3);
            fmae(p0, feat + b0 + ch0);
            fmae(p1, feat + b1 + ch0);
            fmae(p2, feat + b2 + ch0);
            fmae(p3, feat + b3 + ch0);
        }
    }
    // scalar tail
    for (; j < cnt; ++j) {
        unsigned sn = ellp[j];
        unsigned b = sn * FS;
        if (act) {
            float p = pval(sval(b, sn));
            z += p;
            fmae(p, feat + b + ch0);
        }
    }

    // epilogue: v = acc/z + bias -> LayerNorm -> activation
    const float zinv = 1.f / (z + 1e-16f);
    float v[CPL];
    float sum = 0.f, sumsq = 0.f;
#pragma unroll
    for (int c = 0; c < CPL; ++c) v[c] = 0.f;
    if (act) {
#pragma unroll
        for (int c = 0; c < CPL; ++c) {
            v[c] = fmaf(acc[c], zinv, bias[ch0 + c]);
            sum += v[c];
            sumsq += v[c] * v[c];
        }
    }
#pragma unroll
    for (int off = 32; off; off >>= 1) {
        sum += __shfl_xor(sum, off);
        sumsq += __shfl_xor(sumsq, off);
    }
    const float mu = sum / F;
    const float var = sumsq / F - mu * mu;
    const float rstd = rsqrtf(var + LN_EPS);

    if (MODE == 0) {
        if (act) {
            unsigned short yb[CPL];
#pragma unroll
            for (int c = 0; c < CPL; ++c) {
                float y = (v[c] - mu) * rstd * lnw[ch0 + c] + lnb[ch0 + c];
                y = y > 0.f ? y : expm1f(y);  // ELU
                yb[c] = f2bf(y);
            }
            OutT* op = out + (size_t)node * F + ch0;
            if constexpr (CPL == 4) {
                ushort4 st = {yb[0], yb[1], yb[2], yb[3]};
                *reinterpret_cast<ushort4*>(op) = st;
            } else if constexpr (CPL == 2) {
                ushort2 st = {yb[0], yb[1]};
                *reinterpret_cast<ushort2*>(op) = st;
            } else {
                *op = yb[0];
            }
        }
    } else {
        float y = 0.f, mx = -1e30f;
        if (act) {
            y = (v[0] - mu) * rstd * lnw[ch0] + lnb[ch0];
            mx = y;
        }
#pragma unroll
        for (int off = 32; off; off >>= 1) mx = fmaxf(mx, __shfl_xor(mx, off));
        float se = act ? __expf(y - mx) : 0.f;
#pragma unroll
        for (int off = 32; off; off >>= 1) se += __shfl_xor(se, off);
        float lse = logf(se);
        if (act) ((float*)out)[(size_t)node * F + ch0] = y - mx - lse;
    }
}

// ---------------- host launch ----------------

static inline size_t align_up(size_t x) { return (x + 255) & ~(size_t)255; }

extern "C" void kernel_launch(void* const* d_in, const int* in_sizes, int n_in,
                              void* d_out, int out_size, void* d_ws, size_t ws_size,
                              hipStream_t stream) {
    const float* x    = (const float*)d_in[0];
    const int*   eidx = (const int*)d_in[1];
    const float* W1   = (const float*)d_in[2];
    const float* a1s  = (const float*)d_in[3];
    const float* a1d  = (const float*)d_in[4];
    const float* b1   = (const float*)d_in[5];
    const float* ln1w = (const float*)d_in[6];
    const float* ln1b = (const float*)d_in[7];
    const float* W2   = (const float*)d_in[8];
    const float* a2s  = (const float*)d_in[9];
    const float* a2d  = (const float*)d_in[10];
    const float* b2   = (const float*)d_in[11];
    const float* ln2w = (const float*)d_in[12];
    const float* ln2b = (const float*)d_in[13];
    const float* W3   = (const float*)d_in[14];
    const float* a3s  = (const float*)d_in[15];
    const float* a3d  = (const float*)d_in[16];
    const float* b3   = (const float*)d_in[17];
    const float* ln3w = (const float*)d_in[18];
    const float* ln3b = (const float*)d_in[19];

    char* w = (char*)d_ws;
    int* counts = (int*)w;  w += align_up((size_t)NNODES * 4);
    unsigned short* ell = (unsigned short*)w;  w += align_up((size_t)NNODES * ELLW * 2);
    unsigned short* bufA = (unsigned short*)w; w += align_up((size_t)NNODES * 192 * 2);
    unsigned short* bufB = (unsigned short*)w; w += align_up((size_t)NNODES * 192 * 2);
    float* sbuf = (float*)w; w += align_up((size_t)NNODES * 8 * 4);
    float* tbuf = (float*)w; w += align_up((size_t)NNODES * 8 * 4);
    unsigned short* wt1 = (unsigned short*)w; w += align_up((size_t)W1SZ * 2);
    unsigned short* wt2 = (unsigned short*)w; w += align_up((size_t)W2SZ * 2);
    unsigned short* wt3 = (unsigned short*)w; w += align_up((size_t)W3SZ * 2);

    const int BS = 256;
    const int PREP_N = W1SZ + W2SZ + W3SZ;   // 72192 > NNODES, covers counts/ELL init too
    prep_kernel<<<(PREP_N + BS - 1) / BS, BS, 0, stream>>>(W1, W2, W3, wt1, wt2, wt3, counts, ell);

    const int G1 = NNODES / 16;               // 3125 gemm blocks (1 row-tile/block, WSPLIT=4)
    const int G2 = (NNODES + 31) / 32;        // 1563: 2 row-tiles/block, WSPLIT=2
    const int G3 = (NNODES + 63) / 64;        // 782: 4 row-tiles/block, WSPLIT=1
    const int FILL_NB  = (NEDGES + BS - 1) / BS;  // 3125 edge blocks (appended after gemm blocks)
    const int GRID_AGG = (NNODES + 3) / 4;

    // ---- layer 1: 256 -> H=6,D=32 (F=192, stride 192), fused s/t + ELL fill (appended) ----
    gemmst_kernel<256, 192, 192, 192, 6, 32, 8, 4, 2, false, true, false>
        <<<G1 + FILL_NB, BS, 0, stream>>>(x, wt1, bufA, a1s, a1d, sbuf, tbuf, NNODES,
                                          G1, eidx, counts, ell, NEDGES);
    agg10_kernel<6, 32, 192, 4, 8, 0, 0, unsigned short><<<GRID_AGG, BS, 0, stream>>>(bufA, sbuf, tbuf, counts, ell, b1, ln1w, ln1b, bufB, NNODES);

    // ---- layer 2: 192 -> H=3,D=32 (F=96, stride 128 = 2 lines; s embedded at shorts 96..101) ----
    gemmst_kernel<192, 96, 128, 96, 3, 32, 4, 2, 2, true, false, true>
        <<<G2, BS, 0, stream>>>(bufB, wt2, bufA, a2s, a2d, sbuf, tbuf, NNODES,
                                G2, nullptr, nullptr, nullptr, 0);
    agg10_kernel<3, 32, 128, 2, 4, 96, 0, unsigned short><<<GRID_AGG, BS, 0, stream>>>(bufA, sbuf, tbuf, counts, ell, b2, ln2w, ln2b, bufB, NNODES);

    // ---- layer 3: 96 -> H=1,D=40 (F=40, stride 64 = 1 line; s embedded at shorts 40..41) ----
    gemmst_kernel<96, 40, 64, 48, 1, 40, 1, 1, 1, true, false, true>
        <<<G3, BS, 0, stream>>>(bufB, wt3, bufA, a3s, a3d, sbuf, tbuf, NNODES,
                                G3, nullptr, nullptr, nullptr, 0);
    agg10_kernel<1, 40, 64, 1, 1, 40, 1, float><<<GRID_AGG, BS, 0, stream>>>(bufA, sbuf, tbuf, counts, ell, b3, ln3w, ln3b, (float*)d_out, NNODES);
}